// Round 3
// baseline (167.503 us; speedup 1.0000x reference)
//
#include <hip/hip_runtime.h>

// QuantileLoss: mean over [ (p0-t0)^2, (p1-t1)^2, (p2-t2)^2, lower, upper ]
//   lower = p3>p2 ? (p4-t2)*4 : (p3>0.95*t2 ? 0 : (p3-0.95*t2)^2)
//   upper = p4<p2 ? (p4-t2)*4 : (p4<1.05*t2 ? 0 : (p4-1.05*t2)^2)
//
// R1/R2: single-address atomicAdd(double) serialized -> per-block partials.
// R3 (157.4us): wave-private 64-row LDS tiles, 1024 blocks: ql_main=50.6us,
//   2.65 TB/s effective, Occupancy 31%.
// R4 (160.8us): 2048 blocks + 2-deep per-wave pipeline: Occupancy 31->56%,
//   MLP 2x -> ql_main UNCHANGED (50.2us, 2.67 TB/s). Null result => not
//   latency/MLP-bound; a server is saturated. FETCH_SIZE=65.5MB of 134MB
//   => stream is ~half L3-hit / half HBM.
// R5: compile error — __builtin_nontemporal_load needs a native clang vector
//   type, not HIP_vector_type<float,4>. Fixed here with ext_vector_type(4).
// R6 (this, same experiment as R5 intended):
//   (a) NO LDS: 4 rows/thread = 5 aligned float4 (preds) + 3 (target),
//       static register indexing after unroll -> the ds_write/lgkm/ds_read
//       chain disappears entirely; loads go straight to registers.
//   (b) NON-TEMPORAL loads: zero reuse within the kernel; NT stops L3
//       allocation -> steady-state becomes a pure HBM read stream ->
//       FETCH_SIZE should jump to ~134MB, testing whether the mixed
//       L3/HBM stream was the slow server.
//   If this still sits at ~50us with FETCH~134MB, the read-direction
//   ceiling (~2.7 TB/s for this pattern) is real -> roofline.

#define BLOCK 256
#define NBLK  2048

typedef float f4 __attribute__((ext_vector_type(4)));

__device__ __forceinline__ float row_loss(float p0, float p1, float p2,
                                          float p3, float p4,
                                          float t0, float t1, float t2) {
    float d0 = p0 - t0, d1 = p1 - t1, d2 = p2 - t2;
    float acc = d0 * d0 + d1 * d1 + d2 * d2;
    float tl = t2 * 0.95f;
    float tu = t2 * 1.05f;
    float pen = (p4 - t2) * 4.0f;
    float dl = p3 - tl;
    float du = p4 - tu;
    float lower = (p3 > p2) ? pen : ((p3 > tl) ? 0.0f : dl * dl);
    float upper = (p4 < p2) ? pen : ((p4 < tu) ? 0.0f : du * du);
    return acc + lower + upper;
}

__global__ __launch_bounds__(BLOCK) void ql_main(const float* __restrict__ preds,
                                                 const float* __restrict__ target,
                                                 double* __restrict__ ws,
                                                 long ngroups) {
    __shared__ double wsum[BLOCK / 64];

    const f4* pb4 = (const f4*)preds;
    const f4* tb4 = (const f4*)target;
    const long T = (long)gridDim.x * BLOCK;

    float acc = 0.0f;

    // one "group" = 4 consecutive rows: preds 80B = 5 float4, target 48B = 3 float4
    for (long g = (long)blockIdx.x * BLOCK + threadIdx.x; g < ngroups; g += T) {
        const f4* p = pb4 + g * 5;
        const f4* q = tb4 + g * 3;
        f4 r0 = __builtin_nontemporal_load(p + 0);
        f4 r1 = __builtin_nontemporal_load(p + 1);
        f4 r2 = __builtin_nontemporal_load(p + 2);
        f4 r3 = __builtin_nontemporal_load(p + 3);
        f4 r4 = __builtin_nontemporal_load(p + 4);
        f4 s0 = __builtin_nontemporal_load(q + 0);
        f4 s1 = __builtin_nontemporal_load(q + 1);
        f4 s2 = __builtin_nontemporal_load(q + 2);

        // rows laid out flat: pred row j = floats 5j..5j+4, target row j = 3j..3j+2
        acc += row_loss(r0.x, r0.y, r0.z, r0.w, r1.x, s0.x, s0.y, s0.z);
        acc += row_loss(r1.y, r1.z, r1.w, r2.x, r2.y, s0.w, s1.x, s1.y);
        acc += row_loss(r2.z, r2.w, r3.x, r3.y, r3.z, s1.z, s1.w, s2.x);
        acc += row_loss(r3.w, r4.x, r4.y, r4.z, r4.w, s2.y, s2.z, s2.w);
    }

    // wave reduction (double), cross-wave via LDS, one plain store per block
    double dacc = (double)acc;
#pragma unroll
    for (int off = 32; off > 0; off >>= 1)
        dacc += __shfl_down(dacc, off, 64);
    const int lane = threadIdx.x & 63;
    const int w = threadIdx.x >> 6;
    if (lane == 0) wsum[w] = dacc;
    __syncthreads();
    if (threadIdx.x == 0)
        ws[blockIdx.x] = wsum[0] + wsum[1] + wsum[2] + wsum[3];
}

__global__ __launch_bounds__(256) void ql_finalize(const double* __restrict__ ws,
                                                   const float* __restrict__ preds,
                                                   const float* __restrict__ target,
                                                   float* __restrict__ out,
                                                   long rows, long tail_start) {
    __shared__ double wsum[4];
    const int tid = threadIdx.x;

    double d = 0.0;
#pragma unroll
    for (int i = 0; i < NBLK / 256; ++i)
        d += ws[tid + i * 256];

    // leftover rows not covered by full 4-row groups (none for N=4194304)
    long r = tail_start + tid;
    if (r < rows) {
        const float* p = preds + r * 5;
        const float* tg = target + r * 3;
        d += (double)row_loss(p[0], p[1], p[2], p[3], p[4], tg[0], tg[1], tg[2]);
    }

#pragma unroll
    for (int off = 32; off > 0; off >>= 1)
        d += __shfl_down(d, off, 64);
    int lane = tid & 63, w = tid >> 6;
    if (lane == 0) wsum[w] = d;
    __syncthreads();
    if (tid == 0) {
        double total = wsum[0] + wsum[1] + wsum[2] + wsum[3];
        out[0] = (float)(total / ((double)rows * 5.0));
    }
}

extern "C" void kernel_launch(void* const* d_in, const int* in_sizes, int n_in,
                              void* d_out, int out_size, void* d_ws, size_t ws_size,
                              hipStream_t stream) {
    const float* preds = (const float*)d_in[0];
    const float* target = (const float*)d_in[1];
    long rows = (long)in_sizes[0] / 5;
    long ngroups = rows / 4;            // full 4-row groups
    long tail_start = ngroups * 4;

    double* partials = (double*)d_ws;   // NBLK doubles = 16 KB

    ql_main<<<NBLK, BLOCK, 0, stream>>>(preds, target, partials, ngroups);
    ql_finalize<<<1, 256, 0, stream>>>(partials, preds, target,
                                       (float*)d_out, rows, tail_start);
}

// Round 4
// 158.970 us; speedup vs baseline: 1.0537x; 1.0537x over previous
//
#include <hip/hip_runtime.h>

// QuantileLoss: mean over [ (p0-t0)^2, (p1-t1)^2, (p2-t2)^2, lower, upper ]
//   lower = p3>p2 ? (p4-t2)*4 : (p3>0.95*t2 ? 0 : (p3-0.95*t2)^2)
//   upper = p4<p2 ? (p4-t2)*4 : (p4<1.05*t2 ? 0 : (p4-1.05*t2)^2)
//
// R1/R2: single-address atomicAdd(double) serialized -> per-block partials.
// R3 (157.7us): wave-private 64-row LDS tiles, 1024 blocks: ql_main=50.6us.
// R4 (160.8us): 2048 blocks + 2-deep pipeline: Occupancy 31->56%, MLP 2x,
//   ql_main UNCHANGED (50.2us). => not latency/MLP-bound.
// R6 (167.5us): no-LDS register kernel + NONTEMPORAL loads. ql_main dropped
//   below the ~49.5us harness fills (out of top-5) but scored total REGRESSED:
//   NT stops L3 re-allocation, so the scored loop loses the ~50% L3-hit
//   stream (R3/R4 FETCH_SIZE=65.5MB of 134MB).
// Ceiling model (corrected): "6.3 TB/s achievable" is a copy (R+W sum)
//   figure. Read-direction evidence: m13 copy read-component ~3.15 TB/s,
//   RMSNorm/LN ~2.5 TB/s/direction, and three structurally different
//   kernels here all pinned at 2.67 TB/s read-only with MLP varied 4x.
//   => read-only service ceiling in this context ~2.7-3.2 TB/s; ql_main at
//   ~85-90% of it. The fills' 6.7 TB/s is write-direction.
// R7 (this): restore best config + take the small remaining headroom:
//   - plain (temporal) float4 loads -> L3 residency back;
//   - no-LDS register kernel, 4 rows/thread (5+3 aligned float4), VGPR~64
//     -> 32 waves/CU occupancy cap;
//   - 4096 blocks = exactly 1 group/thread at N=4194304: no loop overhead,
//     cross-block turnover (16 blocks/CU) provides free pipelining.

#define BLOCK 256
#define NBLK  4096

typedef float f4 __attribute__((ext_vector_type(4)));

__device__ __forceinline__ float row_loss(float p0, float p1, float p2,
                                          float p3, float p4,
                                          float t0, float t1, float t2) {
    float d0 = p0 - t0, d1 = p1 - t1, d2 = p2 - t2;
    float acc = d0 * d0 + d1 * d1 + d2 * d2;
    float tl = t2 * 0.95f;
    float tu = t2 * 1.05f;
    float pen = (p4 - t2) * 4.0f;
    float dl = p3 - tl;
    float du = p4 - tu;
    float lower = (p3 > p2) ? pen : ((p3 > tl) ? 0.0f : dl * dl);
    float upper = (p4 < p2) ? pen : ((p4 < tu) ? 0.0f : du * du);
    return acc + lower + upper;
}

__global__ __launch_bounds__(BLOCK) void ql_main(const float* __restrict__ preds,
                                                 const float* __restrict__ target,
                                                 double* __restrict__ ws,
                                                 long ngroups) {
    __shared__ double wsum[BLOCK / 64];

    const f4* pb4 = (const f4*)preds;
    const f4* tb4 = (const f4*)target;
    const long T = (long)gridDim.x * BLOCK;

    float acc = 0.0f;

    // one "group" = 4 consecutive rows: preds 80B = 5 float4, target 48B = 3 float4
    // (grid-stride loop executes exactly once at N=4194304 with 4096x256)
    for (long g = (long)blockIdx.x * BLOCK + threadIdx.x; g < ngroups; g += T) {
        const f4* p = pb4 + g * 5;
        const f4* q = tb4 + g * 3;
        f4 r0 = p[0];
        f4 r1 = p[1];
        f4 r2 = p[2];
        f4 r3 = p[3];
        f4 r4 = p[4];
        f4 s0 = q[0];
        f4 s1 = q[1];
        f4 s2 = q[2];

        // rows laid out flat: pred row j = floats 5j..5j+4, target row j = 3j..3j+2
        acc += row_loss(r0.x, r0.y, r0.z, r0.w, r1.x, s0.x, s0.y, s0.z);
        acc += row_loss(r1.y, r1.z, r1.w, r2.x, r2.y, s0.w, s1.x, s1.y);
        acc += row_loss(r2.z, r2.w, r3.x, r3.y, r3.z, s1.z, s1.w, s2.x);
        acc += row_loss(r3.w, r4.x, r4.y, r4.z, r4.w, s2.y, s2.z, s2.w);
    }

    // wave reduction (double), cross-wave via LDS, one plain store per block
    double dacc = (double)acc;
#pragma unroll
    for (int off = 32; off > 0; off >>= 1)
        dacc += __shfl_down(dacc, off, 64);
    const int lane = threadIdx.x & 63;
    const int w = threadIdx.x >> 6;
    if (lane == 0) wsum[w] = dacc;
    __syncthreads();
    if (threadIdx.x == 0)
        ws[blockIdx.x] = wsum[0] + wsum[1] + wsum[2] + wsum[3];
}

__global__ __launch_bounds__(256) void ql_finalize(const double* __restrict__ ws,
                                                   const float* __restrict__ preds,
                                                   const float* __restrict__ target,
                                                   float* __restrict__ out,
                                                   long rows, long tail_start) {
    __shared__ double wsum[4];
    const int tid = threadIdx.x;

    double d = 0.0;
#pragma unroll
    for (int i = 0; i < NBLK / 256; ++i)
        d += ws[tid + i * 256];

    // leftover rows not covered by full 4-row groups (none for N=4194304)
    long r = tail_start + tid;
    if (r < rows) {
        const float* p = preds + r * 5;
        const float* tg = target + r * 3;
        d += (double)row_loss(p[0], p[1], p[2], p[3], p[4], tg[0], tg[1], tg[2]);
    }

#pragma unroll
    for (int off = 32; off > 0; off >>= 1)
        d += __shfl_down(d, off, 64);
    int lane = tid & 63, w = tid >> 6;
    if (lane == 0) wsum[w] = d;
    __syncthreads();
    if (tid == 0) {
        double total = wsum[0] + wsum[1] + wsum[2] + wsum[3];
        out[0] = (float)(total / ((double)rows * 5.0));
    }
}

extern "C" void kernel_launch(void* const* d_in, const int* in_sizes, int n_in,
                              void* d_out, int out_size, void* d_ws, size_t ws_size,
                              hipStream_t stream) {
    const float* preds = (const float*)d_in[0];
    const float* target = (const float*)d_in[1];
    long rows = (long)in_sizes[0] / 5;
    long ngroups = rows / 4;            // full 4-row groups
    long tail_start = ngroups * 4;

    double* partials = (double*)d_ws;   // NBLK doubles = 32 KB

    ql_main<<<NBLK, BLOCK, 0, stream>>>(preds, target, partials, ngroups);
    ql_finalize<<<1, 256, 0, stream>>>(partials, preds, target,
                                       (float*)d_out, rows, tail_start);
}